// Round 3
// baseline (203.411 us; speedup 1.0000x reference)
//
#include <hip/hip_runtime.h>
#include <hip/hip_bf16.h>

// BertCrf: B=64, S=512, H=768, L=9
// K1 feats: feats[b,s,l] = dot(hidden[b,s,:], W[l,:]) + b[l]  (HBM-bound, 96MB; DPP reduce)
// K2 chunk: per-(b,chunk) log-semiring product of 16 transition matrices (LDS double-buffer)
// K3 combine: fold 32 chunk matrices + numerator score + atomic mean into d_out
#define BB 64
#define SS 512
#define HH 768
#define LL 9
#define CL 16
#define NC (SS / CL)
#define NEG (-1e30f)

#define EXP2F(x) exp2f(x)     // v_exp_f32 (log2 domain throughout)
#define LOG2F(x) __log2f(x)   // v_log_f32

static __device__ __forceinline__ float dot4(float4 a, float4 b) {
    return a.x * b.x + a.y * b.y + a.z * b.z + a.w * b.w;
}

static __device__ __forceinline__ float max9(const float* v) {
    float m1 = fmaxf(fmaxf(v[0], v[1]), v[2]);   // v_max3
    float m2 = fmaxf(fmaxf(v[3], v[4]), v[5]);
    float m3 = fmaxf(fmaxf(v[6], v[7]), v[8]);
    return fmaxf(fmaxf(m1, m2), m3);
}

static __device__ __forceinline__ float sum9exp(const float* v, float mx) {
    float e0 = EXP2F(v[0] - mx), e1 = EXP2F(v[1] - mx), e2 = EXP2F(v[2] - mx);
    float e3 = EXP2F(v[3] - mx), e4 = EXP2F(v[4] - mx), e5 = EXP2F(v[5] - mx);
    float e6 = EXP2F(v[6] - mx), e7 = EXP2F(v[7] - mx), e8 = EXP2F(v[8] - mx);
    return ((e0 + e1) + (e2 + e3)) + (((e4 + e5) + (e6 + e7)) + e8);  // tree, short chain
}

// DPP add: VALU pipe, no LDS traffic.
template <int CTRL>
static __device__ __forceinline__ float dpp_add(float v) {
    return v + __int_as_float(
        __builtin_amdgcn_update_dpp(0, __float_as_int(v), CTRL, 0xF, 0xF, true));
}

// Full 64-lane sum: 4 DPP steps within 16-lane rows (xor1, xor2, ror4, ror8 —
// rotations are sum-equivalent), then 2 cross-group shuffles. 2 LDS-pipe ops vs 6.
static __device__ __forceinline__ float wave_sum64(float v) {
    v = dpp_add<0xB1>(v);    // quad_perm [1,0,3,2]  == xor 1
    v = dpp_add<0x4E>(v);    // quad_perm [2,3,0,1]  == xor 2
    v = dpp_add<0x124>(v);   // row_ror:4
    v = dpp_add<0x128>(v);   // row_ror:8  -> full 16-lane row sum
    v += __shfl_xor(v, 16);
    v += __shfl_xor(v, 32);
    return v;
}

// ---------------- K1: emissions ----------------
// One wave per row (64 lanes x 12 cols), W in registers (27 float4 = 108 VGPR).
// 2-row unroll: 6 dwordx4 loads in flight per iteration.
__global__ __launch_bounds__(256, 2)
void feats_kernel(const float* __restrict__ hidden,
                  const float* __restrict__ W,
                  const float* __restrict__ bias,
                  float* __restrict__ feats,
                  float* __restrict__ out0) {
    if (blockIdx.x == 0 && threadIdx.x == 0) out0[0] = 0.f;  // init for K3's atomic mean

    const int lane = threadIdx.x & 63;
    const int wv   = threadIdx.x >> 6;
    const int gw   = blockIdx.x * 4 + wv;
    const int nw   = 4096;                 // 1024 blocks * 4 waves

    float4 wreg[3][LL];
#pragma unroll
    for (int c = 0; c < 3; ++c)
#pragma unroll
        for (int l = 0; l < LL; ++l)
            wreg[c][l] = *(const float4*)(W + l * HH + c * 256 + (lane << 2));

    const float bv = bias[lane < LL ? lane : 0];

    for (int r0 = gw; r0 < BB * SS; r0 += 2 * nw) {   // 4 iterations, r1 always valid
        const int r1 = r0 + nw;
        const float4* h0p = (const float4*)(hidden + (size_t)r0 * HH);
        const float4* h1p = (const float4*)(hidden + (size_t)r1 * HH);
        float4 a0 = h0p[lane], a1 = h0p[64 + lane], a2 = h0p[128 + lane];
        float4 b0 = h1p[lane], b1 = h1p[64 + lane], b2 = h1p[128 + lane];

        float accA[LL], accB[LL];
#pragma unroll
        for (int l = 0; l < LL; ++l) {
            accA[l] = dot4(a0, wreg[0][l]) + dot4(a1, wreg[1][l]) + dot4(a2, wreg[2][l]);
            accB[l] = dot4(b0, wreg[0][l]) + dot4(b1, wreg[1][l]) + dot4(b2, wreg[2][l]);
        }
        float outA = 0.f, outB = 0.f;
#pragma unroll
        for (int l = 0; l < LL; ++l) {
            float sA = wave_sum64(accA[l]);
            float sB = wave_sum64(accB[l]);
            if (lane == l) { outA = sA; outB = sB; }   // static select, regs only
        }
        if (lane < LL) {
            feats[(size_t)r0 * LL + lane] = outA + bv;
            feats[(size_t)r1 * LL + lane] = outB + bv;
        }
    }
}

// ---------------- K2: chunked log-semiring matrix products ----------------
// 192 threads: entry (i,j) at tid=i*16+j (i<9, j<9 active). Running product's row i
// staged in a double-buffered LDS tile (1.5KB); 1 barrier/step. fs[] fully
// static-indexed (unrolled, predicated on block-uniform na) so it stays in VGPRs.
__global__ __launch_bounds__(192, 6)
void crf_chunk_kernel(const float* __restrict__ feats,
                      const float* __restrict__ trans,
                      const int* __restrict__ mask,
                      float* __restrict__ Q) {
    __shared__ float Pb[2][12][16];
    const float INV_LN2 = 1.4426950408889634f;
    const int b   = blockIdx.x / NC;
    const int c   = blockIdx.x % NC;
    const int tid = threadIdx.x;
    const int i   = tid >> 4;
    const int j   = tid & 15;
    const int jc  = j < LL ? j : LL - 1;

    float trC[LL];
#pragma unroll
    for (int k = 0; k < LL; ++k) trC[k] = trans[k * LL + jc] * INV_LN2;

    const int t0    = (c == 0) ? 1 : c * CL;
    const int steps = (c + 1) * CL - t0;          // 15 or 16

    const float* fb = feats + (size_t)b * SS * LL;
    const int*   mb = mask + b * SS;

    float fs[CL];
    int   na = 0;
#pragma unroll
    for (int s = 0; s < CL; ++s) {
        if (s < steps) {
            const int t = t0 + s;
            fs[s] = fb[t * LL + jc] * INV_LN2;
            na += (mb[t] != 0) ? 1 : 0;           // mask monotone
        } else {
            fs[s] = 0.f;
        }
    }

    float P = (i == j) ? 0.f : NEG;               // log-semiring identity
    Pb[0][i][j] = P;
    __syncthreads();

#pragma unroll
    for (int s = 0; s < CL; ++s) {                // static unroll: fs, s&1 all compile-time
        if (s < na) {                              // na uniform across block -> scalar branch
            const float* row = &Pb[s & 1][i][0];
            float v[LL];
#pragma unroll
            for (int k = 0; k < LL; ++k) v[k] = row[k] + trC[k];
            const float mx  = max9(v);
            const float sum = sum9exp(v, mx);
            P = mx + LOG2F(sum) + fs[s];
            Pb[(s + 1) & 1][i][j] = P;            // write next buffer
        }
        __syncthreads();                          // all threads: write(s) visible before read(s+1)
    }

    if (i < LL && j < LL)
        Q[((size_t)(b * NC + c)) * (LL * LL) + i * LL + j] = P;
}

// ---------------- K3: fold chunks + numerator score + atomic mean ----------------
__global__ __launch_bounds__(64, 1)
void crf_combine_kernel(const float* __restrict__ feats,
                        const float* __restrict__ Q,
                        const float* __restrict__ start_t,
                        const float* __restrict__ end_t,
                        const float* __restrict__ trans,
                        const int* __restrict__ labels,
                        const int* __restrict__ mask,
                        float* __restrict__ out) {
    const int b    = blockIdx.x;
    const int lane = threadIdx.x;
    const int j    = lane < LL ? lane : LL - 1;
    const float INV_LN2 = 1.4426950408889634f;
    const float LN2     = 0.6931471805599453f;

    const float* fb = feats + (size_t)b * SS * LL;
    const int*   lb = labels + b * SS;
    const int*   mb = mask + b * SS;
    const float* Qb = Q + (size_t)b * NC * (LL * LL);

    // numerator score + sequence length
    float partial = 0.f;
    int   cnt     = 0;
    for (int t = lane; t < SS; t += 64) {
        const int m = mb[t];
        cnt += (m != 0);
        if (t >= 1 && m) {
            const int lp = lb[t - 1], lc = lb[t];
            partial += trans[lp * LL + lc] + fb[t * LL + lc];
        }
    }
#pragma unroll
    for (int off = 1; off < 64; off <<= 1) {
        partial += __shfl_xor(partial, off);
        cnt     += __shfl_xor(cnt, off);
    }

    // alpha0, then fold 32 chunk matrices (prefetch next column off the chain)
    float alpha[LL];
#pragma unroll
    for (int k = 0; k < LL; ++k) alpha[k] = (start_t[k] + fb[k]) * INV_LN2;

    float qcol[LL], qnext[LL];
#pragma unroll
    for (int k = 0; k < LL; ++k) qnext[k] = Qb[k * LL + j];
    for (int c = 0; c < NC; ++c) {
#pragma unroll
        for (int k = 0; k < LL; ++k) qcol[k] = qnext[k];
        if (c + 1 < NC) {
            const float* Qn = Qb + (size_t)(c + 1) * (LL * LL);
#pragma unroll
            for (int k = 0; k < LL; ++k) qnext[k] = Qn[k * LL + j];
        }
        float v[LL];
#pragma unroll
        for (int k = 0; k < LL; ++k) v[k] = alpha[k] + qcol[k];
        const float mx  = max9(v);
        const float sum = sum9exp(v, mx);
        const float anew = mx + LOG2F(sum);
#pragma unroll
        for (int k = 0; k < LL; ++k)
            alpha[k] = __uint_as_float(__builtin_amdgcn_readlane(__float_as_uint(anew), k));
    }

    // log_den = LSE(alpha + end)
    float v[LL];
#pragma unroll
    for (int k = 0; k < LL; ++k) v[k] = alpha[k] + end_t[k] * INV_LN2;
    const float mx  = max9(v);
    const float sum = sum9exp(v, mx);
    const float log_den = (mx + LOG2F(sum)) * LN2;

    if (lane == 0) {
        const int l0 = lb[0];
        const float score = start_t[l0] + fb[l0] + partial + end_t[lb[cnt - 1]];
        atomicAdd(out, (log_den - score) * (1.0f / BB));   // device-scope, XCD-safe
    }
}

extern "C" void kernel_launch(void* const* d_in, const int* in_sizes, int n_in,
                              void* d_out, int out_size, void* d_ws, size_t ws_size,
                              hipStream_t stream) {
    const float* hidden = (const float*)d_in[0];
    const float* W      = (const float*)d_in[1];
    const float* bias   = (const float*)d_in[2];
    const float* startT = (const float*)d_in[3];
    const float* endT   = (const float*)d_in[4];
    const float* trans  = (const float*)d_in[5];
    const int*   labels = (const int*)d_in[6];
    const int*   mask   = (const int*)d_in[7];

    float* feats = (float*)d_ws;                       // B*S*L fp32 = 1.18 MB
    float* Q     = feats + (size_t)BB * SS * LL;       // B*NC*81 fp32 = 664 KB

    feats_kernel<<<dim3(1024), dim3(256), 0, stream>>>(hidden, W, bias, feats, (float*)d_out);
    crf_chunk_kernel<<<dim3(BB * NC), dim3(192), 0, stream>>>(feats, trans, mask, Q);
    crf_combine_kernel<<<dim3(BB), dim3(64), 0, stream>>>(feats, Q, startT, endT, trans,
                                                          labels, mask, (float*)d_out);
}

// Round 4
// 192.345 us; speedup vs baseline: 1.0575x; 1.0575x over previous
//
#include <hip/hip_runtime.h>
#include <hip/hip_bf16.h>

// BertCrf: B=64, S=512, H=768, L=9
// K1 fused: one block per (b,chunk): emissions for its 16 rows (W in regs, DPP reduce)
//           -> LDS -> 16-step log-semiring product + numerator-score partial.
// K2 combine: per b: fold 32 chunk matrices, sum 32 score partials, atomic mean.
#define BB 64
#define SS 512
#define HH 768
#define LL 9
#define CL 16
#define NC (SS / CL)          // 32
#define NEG (-1e30f)

#define EXP2F(x) exp2f(x)     // v_exp_f32 (log2 domain)
#define LOG2F(x) __log2f(x)   // v_log_f32

static __device__ __forceinline__ float dot4(float4 a, float4 b) {
    return a.x * b.x + a.y * b.y + a.z * b.z + a.w * b.w;
}

static __device__ __forceinline__ float max9(const float* v) {
    float m1 = fmaxf(fmaxf(v[0], v[1]), v[2]);   // v_max3 chains
    float m2 = fmaxf(fmaxf(v[3], v[4]), v[5]);
    float m3 = fmaxf(fmaxf(v[6], v[7]), v[8]);
    return fmaxf(fmaxf(m1, m2), m3);
}

static __device__ __forceinline__ float sum9exp(const float* v, float mx) {
    float e0 = EXP2F(v[0] - mx), e1 = EXP2F(v[1] - mx), e2 = EXP2F(v[2] - mx);
    float e3 = EXP2F(v[3] - mx), e4 = EXP2F(v[4] - mx), e5 = EXP2F(v[5] - mx);
    float e6 = EXP2F(v[6] - mx), e7 = EXP2F(v[7] - mx), e8 = EXP2F(v[8] - mx);
    return ((e0 + e1) + (e2 + e3)) + (((e4 + e5) + (e6 + e7)) + e8);
}

template <int CTRL>
static __device__ __forceinline__ float dpp_add(float v) {
    return v + __int_as_float(
        __builtin_amdgcn_update_dpp(0, __float_as_int(v), CTRL, 0xF, 0xF, true));
}

// 64-lane sum: 4 DPP steps (VALU pipe) + 2 cross-group shuffles.
static __device__ __forceinline__ float wave_sum64(float v) {
    v = dpp_add<0xB1>(v);    // quad_perm [1,0,3,2] == xor 1
    v = dpp_add<0x4E>(v);    // quad_perm [2,3,0,1] == xor 2
    v = dpp_add<0x124>(v);   // row_ror:4
    v = dpp_add<0x128>(v);   // row_ror:8  -> 16-lane row sum
    v += __shfl_xor(v, 16);
    v += __shfl_xor(v, 32);
    return v;
}

// ---------------- K1: fused emissions + chunk product + score partial ----------------
__global__ __launch_bounds__(256, 2)
void fused_kernel(const float* __restrict__ hidden,
                  const float* __restrict__ W,
                  const float* __restrict__ bias,
                  const float* __restrict__ start_t,
                  const float* __restrict__ end_t,
                  const float* __restrict__ trans,
                  const int* __restrict__ labels,
                  const int* __restrict__ mask,
                  float* __restrict__ Q,      // [BB*NC][81]
                  float* __restrict__ A0,     // [BB][16]
                  float* __restrict__ Sc,     // [BB*NC]
                  float* __restrict__ out0) {
    const int bid  = blockIdx.x;
    const int b    = bid >> 5;               // NC = 32
    const int c    = bid & (NC - 1);
    const int tid  = threadIdx.x;
    const int lane = tid & 63;
    const int wv   = tid >> 6;

    if (bid == 0 && tid == 0) out0[0] = 0.f;   // init for K2's atomic mean

    __shared__ float fsl[CL][12];              // 16 emission rows x 9 (padded)
    __shared__ float Pb[2][LL][16];            // double-buffered running product

    const int bS     = b * SS;
    const int t_base = c * CL;

    // ---- early independent loads (hide under emission compute) ----
    const int i  = tid >> 4;                   // product row (tid<144 active)
    const int j  = tid & 15;                   // product col (j<9 active)
    const int jc = j < LL ? j : LL - 1;
    const float INV_LN2 = 1.4426950408889634f;

    float trC[LL];
#pragma unroll
    for (int k = 0; k < LL; ++k) trC[k] = trans[k * LL + jc] * INV_LN2;

    const int off   = (c == 0) ? 1 : 0;        // chunk 0 starts at t=1
    const int steps = CL - off;                // 15 or 16
    const int t0    = t_base + off;

    // masked-step count for this chunk (mask monotone); static indices only
    int na = 0;
#pragma unroll
    for (int u = 0; u < CL; ++u)
        na += (u < steps && mask[bS + t0 + u] != 0) ? 1 : 0;

    // score-partial integer loads (wave 3, lanes 0..15), issued before the barrier
    int mt = 0, lc = 0, lp = 0, mnext = 0;
    const int t_sc = t_base + lane;
    if (wv == 3 && lane < CL) {
        mt    = mask[bS + t_sc];
        lc    = labels[bS + t_sc];
        lp    = (t_sc >= 1) ? labels[bS + t_sc - 1] : 0;
        mnext = (t_sc == SS - 1) ? 0 : mask[bS + t_sc + 1];
    }

    // ---- emissions: wave wv computes local rows wv*4 .. wv*4+3 ----
    float4 wreg[3][LL];
#pragma unroll
    for (int c3 = 0; c3 < 3; ++c3)
#pragma unroll
        for (int l = 0; l < LL; ++l)
            wreg[c3][l] = *(const float4*)(W + l * HH + c3 * 256 + (lane << 2));
    const float bv = bias[lane < LL ? lane : 0];

    const float* hbase = hidden + ((size_t)bS + t_base) * HH;
#pragma unroll
    for (int pair = 0; pair < 2; ++pair) {
        const int r0 = wv * 4 + pair * 2;
        const int r1 = r0 + 1;
        const float4* h0p = (const float4*)(hbase + (size_t)r0 * HH);
        const float4* h1p = (const float4*)(hbase + (size_t)r1 * HH);
        float4 a0 = h0p[lane], a1 = h0p[64 + lane], a2 = h0p[128 + lane];
        float4 b0 = h1p[lane], b1 = h1p[64 + lane], b2 = h1p[128 + lane];
        float accA[LL], accB[LL];
#pragma unroll
        for (int l = 0; l < LL; ++l) {
            accA[l] = dot4(a0, wreg[0][l]) + dot4(a1, wreg[1][l]) + dot4(a2, wreg[2][l]);
            accB[l] = dot4(b0, wreg[0][l]) + dot4(b1, wreg[1][l]) + dot4(b2, wreg[2][l]);
        }
        float outA = 0.f, outB = 0.f;
#pragma unroll
        for (int l = 0; l < LL; ++l) {
            float sA = wave_sum64(accA[l]);
            float sB = wave_sum64(accB[l]);
            if (lane == l) { outA = sA; outB = sB; }   // static select
        }
        if (lane < LL) {
            fsl[r0][lane] = outA + bv;
            fsl[r1][lane] = outB + bv;
        }
    }

    // product init (before barrier: Pb untouched by emissions)
    float P = (i == j) ? 0.f : NEG;            // log-semiring identity
    if (tid < 144) Pb[0][i][j] = P;
    __syncthreads();                           // fsl + Pb[0] visible

    // ---- score partial (wave 3; idle in product phase) ----
    if (wv == 3 && lane < CL) {
        float sc = 0.f;
        if (t_sc >= 1 && mt) sc += trans[lp * LL + lc] + fsl[lane][lc];
        if (t_sc == 0)       sc += start_t[lc] + fsl[0][lc];     // unconditional t=0 term
        if (mt && !mnext)    sc += end_t[lc];                     // last masked position
#pragma unroll
        for (int o = 1; o < CL; o <<= 1) sc += __shfl_xor(sc, o);
        if (lane == 0) Sc[bid] = sc;
        if (c == 0 && lane < LL)
            A0[b * 16 + lane] = (start_t[lane] + fsl[0][lane]) * INV_LN2;
    }

    // emission factors for the product, staged to registers (static indices)
    float fsr[CL];
#pragma unroll
    for (int u = 0; u < CL; ++u)
        fsr[u] = (u < steps) ? fsl[u + off][jc] * INV_LN2 : 0.f;

    // ---- 16-step log-semiring product ----
#pragma unroll
    for (int s = 0; s < CL; ++s) {
        if (s < na) {                          // na uniform across block
            if (tid < 144) {
                const float* row = &Pb[s & 1][i][0];
                float v[LL];
#pragma unroll
                for (int k = 0; k < LL; ++k) v[k] = row[k] + trC[k];
                const float mx  = max9(v);
                const float sum = sum9exp(v, mx);
                P = mx + LOG2F(sum) + fsr[s];
                Pb[(s + 1) & 1][i][j] = P;
            }
        }
        __syncthreads();
    }

    if (tid < 144 && j < LL)
        Q[(size_t)bid * (LL * LL) + i * LL + j] = P;
}

// ---------------- K2: fold chunks + score sum + atomic mean ----------------
__global__ __launch_bounds__(64, 1)
void combine_kernel(const float* __restrict__ Q,
                    const float* __restrict__ A0,
                    const float* __restrict__ Sc,
                    const float* __restrict__ end_t,
                    float* __restrict__ out) {
    const int b    = blockIdx.x;
    const int lane = threadIdx.x;
    const int j    = lane < LL ? lane : LL - 1;
    const float INV_LN2 = 1.4426950408889634f;
    const float LN2     = 0.6931471805599453f;

    // sum the 32 score partials
    float score = (lane < NC) ? Sc[b * NC + lane] : 0.f;
#pragma unroll
    for (int o = 1; o < 64; o <<= 1) score += __shfl_xor(score, o);

    // alpha0 (log2 domain), then fold 32 chunk matrices
    float alpha[LL];
#pragma unroll
    for (int k = 0; k < LL; ++k) alpha[k] = A0[b * 16 + k];

    const float* Qb = Q + (size_t)b * NC * (LL * LL);
    float qcol[LL], qnext[LL];
#pragma unroll
    for (int k = 0; k < LL; ++k) qnext[k] = Qb[k * LL + j];
    for (int cc = 0; cc < NC; ++cc) {
#pragma unroll
        for (int k = 0; k < LL; ++k) qcol[k] = qnext[k];
        if (cc + 1 < NC) {
            const float* Qn = Qb + (size_t)(cc + 1) * (LL * LL);
#pragma unroll
            for (int k = 0; k < LL; ++k) qnext[k] = Qn[k * LL + j];
        }
        float v[LL];
#pragma unroll
        for (int k = 0; k < LL; ++k) v[k] = alpha[k] + qcol[k];
        const float mx  = max9(v);
        const float sum = sum9exp(v, mx);
        const float anew = mx + LOG2F(sum);
#pragma unroll
        for (int k = 0; k < LL; ++k)
            alpha[k] = __uint_as_float(__builtin_amdgcn_readlane(__float_as_uint(anew), k));
    }

    // log_den = LSE(alpha + end)
    float v[LL];
#pragma unroll
    for (int k = 0; k < LL; ++k) v[k] = alpha[k] + end_t[k] * INV_LN2;
    const float mx  = max9(v);
    const float sum = sum9exp(v, mx);
    const float log_den = (mx + LOG2F(sum)) * LN2;

    if (lane == 0)
        atomicAdd(out, (log_den - score) * (1.0f / BB));   // device-scope, XCD-safe
}

extern "C" void kernel_launch(void* const* d_in, const int* in_sizes, int n_in,
                              void* d_out, int out_size, void* d_ws, size_t ws_size,
                              hipStream_t stream) {
    const float* hidden = (const float*)d_in[0];
    const float* W      = (const float*)d_in[1];
    const float* bias   = (const float*)d_in[2];
    const float* startT = (const float*)d_in[3];
    const float* endT   = (const float*)d_in[4];
    const float* trans  = (const float*)d_in[5];
    const int*   labels = (const int*)d_in[6];
    const int*   mask   = (const int*)d_in[7];

    float* Q  = (float*)d_ws;                      // 2048*81 fp32 = 663 KB
    float* A0 = Q + (size_t)BB * NC * LL * LL;     // 64*16 fp32
    float* Sc = A0 + BB * 16;                      // 2048 fp32

    fused_kernel<<<dim3(BB * NC), dim3(256), 0, stream>>>(
        hidden, W, bias, startT, endT, trans, labels, mask, Q, A0, Sc, (float*)d_out);
    combine_kernel<<<dim3(BB), dim3(64), 0, stream>>>(Q, A0, Sc, endT, (float*)d_out);
}

// Round 5
// 191.694 us; speedup vs baseline: 1.0611x; 1.0034x over previous
//
#include <hip/hip_runtime.h>
#include <hip/hip_bf16.h>

// BertCrf: B=64, S=512, H=768, L=9
// K1 fused: one block per (b,chunk=8 steps): emissions (W in regs, DPP-16 reduce ->
//           group partials in LDS, no bpermute) + 8-step log-semiring product + score partial.
// K2 combine: per b: fold 64 chunk matrices, sum 64 score partials, atomic mean.
#define BB 64
#define SS 512
#define HH 768
#define LL 9
#define CL 8
#define NC (SS / CL)          // 64
#define NEG (-1e30f)

#define EXP2F(x) exp2f(x)     // v_exp_f32 (log2 domain)
#define LOG2F(x) __log2f(x)   // v_log_f32

static __device__ __forceinline__ float dot4(float4 a, float4 b) {
    return a.x * b.x + a.y * b.y + a.z * b.z + a.w * b.w;
}

static __device__ __forceinline__ float max9(const float* v) {
    float m1 = fmaxf(fmaxf(v[0], v[1]), v[2]);   // v_max3 chains
    float m2 = fmaxf(fmaxf(v[3], v[4]), v[5]);
    float m3 = fmaxf(fmaxf(v[6], v[7]), v[8]);
    return fmaxf(fmaxf(m1, m2), m3);
}

static __device__ __forceinline__ float sum9exp(const float* v, float mx) {
    float e0 = EXP2F(v[0] - mx), e1 = EXP2F(v[1] - mx), e2 = EXP2F(v[2] - mx);
    float e3 = EXP2F(v[3] - mx), e4 = EXP2F(v[4] - mx), e5 = EXP2F(v[5] - mx);
    float e6 = EXP2F(v[6] - mx), e7 = EXP2F(v[7] - mx), e8 = EXP2F(v[8] - mx);
    return ((e0 + e1) + (e2 + e3)) + (((e4 + e5) + (e6 + e7)) + e8);
}

template <int CTRL>
static __device__ __forceinline__ float dpp_add(float v) {
    return v + __int_as_float(
        __builtin_amdgcn_update_dpp(0, __float_as_int(v), CTRL, 0xF, 0xF, true));
}

// 16-lane-row sum, pure VALU pipe (4 DPP steps, no LDS / bpermute).
// All 16 lanes of the row end up holding the row sum.
static __device__ __forceinline__ float group_sum16(float v) {
    v = dpp_add<0xB1>(v);    // quad_perm [1,0,3,2] == xor 1
    v = dpp_add<0x4E>(v);    // quad_perm [2,3,0,1] == xor 2
    v = dpp_add<0x124>(v);   // row_ror:4
    v = dpp_add<0x128>(v);   // row_ror:8
    return v;
}

static __device__ __forceinline__ float lds_sum4(const float* p) {
    float4 q = *(const float4*)p;                 // ds_read_b128, 16B-aligned
    return (q.x + q.y) + (q.z + q.w);
}

// ---------------- K1: fused emissions + chunk product + score partial ----------------
__global__ __launch_bounds__(256, 3)
void fused_kernel(const float* __restrict__ hidden,
                  const float* __restrict__ W,
                  const float* __restrict__ bias,
                  const float* __restrict__ start_t,
                  const float* __restrict__ end_t,
                  const float* __restrict__ trans,
                  const int* __restrict__ labels,
                  const int* __restrict__ mask,
                  float* __restrict__ Q,      // [BB*NC][81]
                  float* __restrict__ A0,     // [BB][16]
                  float* __restrict__ Sc,     // [BB*NC]
                  float* __restrict__ out0) {
    const int bid  = blockIdx.x;
    const int b    = bid >> 6;                 // NC = 64
    const int c    = bid & (NC - 1);
    const int tid  = threadIdx.x;
    const int lane = tid & 63;
    const int wv   = tid >> 6;

    if (bid == 0 && tid == 0) out0[0] = 0.f;   // init for K2's atomic mean

    __shared__ float fsl4[CL][LL][4];          // emission group-partials [row][label][group]
    __shared__ float Pb[2][LL][16];            // double-buffered running product

    const int bS     = b * SS;
    const int t_base = c * CL;
    const float INV_LN2 = 1.4426950408889634f;

    // ---- early thread-uniform / independent loads ----
    const int i  = tid >> 4;                   // product row (tid<144 active)
    const int j  = tid & 15;                   // product col (j<9 active)
    const int jc = j < LL ? j : LL - 1;

    float trC[LL];
#pragma unroll
    for (int k = 0; k < LL; ++k) trC[k] = trans[k * LL + jc] * INV_LN2;
    const float bjc = bias[jc];

    const int off   = (c == 0) ? 1 : 0;        // chunk 0 starts at t=1
    const int steps = CL - off;                // 7 or 8
    const int t0    = t_base + off;

    int na = 0;                                // active steps (mask monotone); s_loads
#pragma unroll
    for (int u = 0; u < CL; ++u)
        na += (u < steps && mask[bS + t0 + u] != 0) ? 1 : 0;

    // score-partial integer loads (wave 3, lanes 0..7), issued before the barrier
    int mt = 0, lc = 0, lp = 0, mnext = 0;
    const int t_sc = t_base + lane;
    if (wv == 3 && lane < CL) {
        mt    = mask[bS + t_sc];
        lc    = labels[bS + t_sc];
        lp    = (t_sc >= 1) ? labels[bS + t_sc - 1] : 0;
        mnext = (t_sc == SS - 1) ? 0 : mask[bS + t_sc + 1];
    }

    // ---- emissions: wave wv owns rows wv*2, wv*2+1; all 6 row-loads in flight ----
    float4 wreg[3][LL];
#pragma unroll
    for (int c3 = 0; c3 < 3; ++c3)
#pragma unroll
        for (int l = 0; l < LL; ++l)
            wreg[c3][l] = *(const float4*)(W + l * HH + c3 * 256 + (lane << 2));

    const float* hbase = hidden + ((size_t)bS + t_base) * HH;
    const int r0 = wv * 2, r1 = r0 + 1;
    const float4* h0p = (const float4*)(hbase + (size_t)r0 * HH);
    const float4* h1p = (const float4*)(hbase + (size_t)r1 * HH);
    float4 a0 = h0p[lane], a1 = h0p[64 + lane], a2 = h0p[128 + lane];
    float4 b0 = h1p[lane], b1 = h1p[64 + lane], b2 = h1p[128 + lane];

    float accA[LL], accB[LL];
#pragma unroll
    for (int l = 0; l < LL; ++l) {
        accA[l] = dot4(a0, wreg[0][l]) + dot4(a1, wreg[1][l]) + dot4(a2, wreg[2][l]);
        accB[l] = dot4(b0, wreg[0][l]) + dot4(b1, wreg[1][l]) + dot4(b2, wreg[2][l]);
    }

    // DPP-16 reduce -> 4 group partials per (row,label); lane sl==l of group g writes.
    const int g  = lane >> 4;
    const int sl = lane & 15;
    float selA = 0.f, selB = 0.f;
#pragma unroll
    for (int l = 0; l < LL; ++l) {
        float rA = group_sum16(accA[l]);
        float rB = group_sum16(accB[l]);
        if (sl == l) { selA = rA; selB = rB; }   // static select, regs only
    }
    if (sl < LL) {
        fsl4[r0][sl][g] = selA;                  // 36 distinct addrs -> ~2-way max
        fsl4[r1][sl][g] = selB;
    }

    float P = (i == j) ? 0.f : NEG;              // log-semiring identity
    if (tid < 144) Pb[0][i][j] = P;
    __syncthreads();                             // fsl4 + Pb[0] visible

    // ---- score partial (wave 3) + A0 (wave 2, c==0 only) ----
    if (wv == 3 && lane < CL) {
        float sc = 0.f;
        if (t_sc >= 1 && mt)
            sc += trans[lp * LL + lc] + lds_sum4(&fsl4[lane][lc][0]) + bias[lc];
        if (t_sc == 0)                           // only c==0, lane==0
            sc += start_t[lc] + lds_sum4(&fsl4[0][lc][0]) + bias[lc];
        if (mt && !mnext) sc += end_t[lc];       // last masked position
#pragma unroll
        for (int o = 1; o < CL; o <<= 1) sc += __shfl_xor(sc, o);
        if (lane == 0) Sc[bid] = sc;
    }
    if (c == 0 && wv == 2 && lane < LL)
        A0[b * 16 + lane] =
            (start_t[lane] + lds_sum4(&fsl4[0][lane][0]) + bias[lane]) * INV_LN2;

    // emission factors for the product (group partials summed, bias added)
    float fsr[CL];
#pragma unroll
    for (int u = 0; u < CL; ++u)
        fsr[u] = (u < steps) ? (lds_sum4(&fsl4[u + off][jc][0]) + bjc) * INV_LN2 : 0.f;

    // ---- 8-step log-semiring product ----
#pragma unroll
    for (int s = 0; s < CL; ++s) {
        if (s < na) {                            // na uniform across block
            if (tid < 144) {
                const float* row = &Pb[s & 1][i][0];
                float v[LL];
#pragma unroll
                for (int k = 0; k < LL; ++k) v[k] = row[k] + trC[k];
                const float mx  = max9(v);
                const float sum = sum9exp(v, mx);
                P = mx + LOG2F(sum) + fsr[s];
                Pb[(s + 1) & 1][i][j] = P;
            }
        }
        __syncthreads();
    }

    if (tid < 144 && j < LL)
        Q[(size_t)bid * (LL * LL) + i * LL + j] = P;
}

// ---------------- K2: fold 64 chunks + score sum + atomic mean ----------------
__global__ __launch_bounds__(64, 1)
void combine_kernel(const float* __restrict__ Q,
                    const float* __restrict__ A0,
                    const float* __restrict__ Sc,
                    const float* __restrict__ end_t,
                    float* __restrict__ out) {
    const int b    = blockIdx.x;
    const int lane = threadIdx.x;
    const int j    = lane < LL ? lane : LL - 1;
    const float INV_LN2 = 1.4426950408889634f;
    const float LN2     = 0.6931471805599453f;

    // sum the 64 score partials
    float score = Sc[b * NC + lane];
#pragma unroll
    for (int o = 1; o < 64; o <<= 1) score += __shfl_xor(score, o);

    // alpha0 (log2 domain), then fold 64 chunk matrices (prefetch next column)
    float alpha[LL];
#pragma unroll
    for (int k = 0; k < LL; ++k) alpha[k] = A0[b * 16 + k];

    const float* Qb = Q + (size_t)b * NC * (LL * LL);
    float qcol[LL], qnext[LL];
#pragma unroll
    for (int k = 0; k < LL; ++k) qnext[k] = Qb[k * LL + j];
    for (int cc = 0; cc < NC; ++cc) {
#pragma unroll
        for (int k = 0; k < LL; ++k) qcol[k] = qnext[k];
        if (cc + 1 < NC) {
            const float* Qn = Qb + (size_t)(cc + 1) * (LL * LL);
#pragma unroll
            for (int k = 0; k < LL; ++k) qnext[k] = Qn[k * LL + j];
        }
        float v[LL];
#pragma unroll
        for (int k = 0; k < LL; ++k) v[k] = alpha[k] + qcol[k];
        const float mx  = max9(v);
        const float sum = sum9exp(v, mx);
        const float anew = mx + LOG2F(sum);
#pragma unroll
        for (int k = 0; k < LL; ++k)
            alpha[k] = __uint_as_float(__builtin_amdgcn_readlane(__float_as_uint(anew), k));
    }

    // log_den = LSE(alpha + end)
    float v[LL];
#pragma unroll
    for (int k = 0; k < LL; ++k) v[k] = alpha[k] + end_t[k] * INV_LN2;
    const float mx  = max9(v);
    const float sum = sum9exp(v, mx);
    const float log_den = (mx + LOG2F(sum)) * LN2;

    if (lane == 0)
        atomicAdd(out, (log_den - score) * (1.0f / BB));   // device-scope, XCD-safe
}

extern "C" void kernel_launch(void* const* d_in, const int* in_sizes, int n_in,
                              void* d_out, int out_size, void* d_ws, size_t ws_size,
                              hipStream_t stream) {
    const float* hidden = (const float*)d_in[0];
    const float* W      = (const float*)d_in[1];
    const float* bias   = (const float*)d_in[2];
    const float* startT = (const float*)d_in[3];
    const float* endT   = (const float*)d_in[4];
    const float* trans  = (const float*)d_in[5];
    const int*   labels = (const int*)d_in[6];
    const int*   mask   = (const int*)d_in[7];

    float* Q  = (float*)d_ws;                      // 4096*81 fp32 = 1.33 MB
    float* A0 = Q + (size_t)BB * NC * LL * LL;     // 64*16 fp32
    float* Sc = A0 + BB * 16;                      // 4096 fp32

    fused_kernel<<<dim3(BB * NC), dim3(256), 0, stream>>>(
        hidden, W, bias, startT, endT, trans, labels, mask, Q, A0, Sc, (float*)d_out);
    combine_kernel<<<dim3(BB), dim3(64), 0, stream>>>(Q, A0, Sc, endT, (float*)d_out);
}